// Round 9
// baseline (119.637 us; speedup 1.0000x reference)
//
#include <hip/hip_runtime.h>
#include <hip/hip_cooperative_groups.h>
#include <hip/hip_bf16.h>
#include <math.h>

#define BB 2
#define TT 2048
#define CC 256
#define HH 4
#define DD 64
#define WW 64
#define TQ 2047
#define NKV 768

namespace cg = cooperative_groups;

typedef __attribute__((ext_vector_type(8))) short bf16x8;
typedef __attribute__((ext_vector_type(4))) float f32x4;

__device__ inline short f2bf(float x) {
    unsigned u = __float_as_uint(x);
    u += 0x7FFF + ((u >> 16) & 1);
    return (short)(u >> 16);
}
__device__ inline float bf2f(short s) {
    return __uint_as_float(((unsigned)(unsigned short)s) << 16);
}
__device__ inline bf16x8 cvt8(float4 a, float4 b) {
    bf16x8 r;
    r[0] = f2bf(a.x); r[1] = f2bf(a.y); r[2] = f2bf(a.z); r[3] = f2bf(a.w);
    r[4] = f2bf(b.x); r[5] = f2bf(b.y); r[6] = f2bf(b.z); r[7] = f2bf(b.w);
    return r;
}

// LDS layout (shorts; phases separated by grid.sync so regions alias):
//  Phase A: As[64][72] @0, Bs[192][72] @4608
//  Phase B: QS @0 [128][72], VT @9216 [64][152], PP @18944 4x[16][104],
//           PD @25600 4x[16][72]; floats @30208: SB[64*68], PT[128*9], DQ[128]
//  Phase C: As16[16][72] @0, Bs[256][72] @1152
#define LDS_SHORTS 41472

__global__ __launch_bounds__(512)
void mega(const float* __restrict__ x, const float* __restrict__ w_kqv,
          const float* __restrict__ w_out, const float* __restrict__ b_out,
          const float* __restrict__ q_pos, const float* __restrict__ v_pos,
          float* __restrict__ y, float* __restrict__ wei_out,
          short* __restrict__ kqvb, short* __restrict__ qposb,
          short* __restrict__ vposTb, short* __restrict__ woutb,
          short* __restrict__ attnSb) {
    __shared__ __align__(16) short lds[LDS_SHORTS];
    cg::grid_group grid = cg::this_grid();

    const int tid  = threadIdx.x;
    const int wv   = tid >> 6;
    const int lane = tid & 63;
    const int col  = lane & 15;
    const int kg   = lane >> 4;
    const int bid  = blockIdx.x;

    // ======================= Phase A: kqv GEMM =======================
    {
        const int m0 = (bid >> 2) * 64, n0 = (bid & 3) * 192;
        const int wr = wv >> 2, wc = wv & 3;
        short* As = lds;            // [64][72]
        short* Bs = lds + 4608;     // [192][72]

        f32x4 acc[2][3];
#pragma unroll
        for (int i = 0; i < 2; ++i)
#pragma unroll
            for (int j = 0; j < 3; ++j) acc[i][j] = (f32x4){0.f, 0.f, 0.f, 0.f};

        for (int k0 = 0; k0 < 256; k0 += 64) {
            {
                int r = tid >> 3, c8 = (tid & 7) << 3;
                const float* ap = x + (size_t)(m0 + r) * 256 + k0 + c8;
                float4 v0 = *reinterpret_cast<const float4*>(ap);
                float4 v1 = *reinterpret_cast<const float4*>(ap + 4);
                *reinterpret_cast<bf16x8*>(&As[r * 72 + c8]) = cvt8(v0, v1);
            }
#pragma unroll
            for (int it = 0; it < 3; ++it) {
                int fi = tid + it * 512;
                int r = fi >> 3, c8 = (fi & 7) << 3;
                const float* bp = w_kqv + (size_t)(n0 + r) * 256 + k0 + c8;
                float4 v0 = *reinterpret_cast<const float4*>(bp);
                float4 v1 = *reinterpret_cast<const float4*>(bp + 4);
                *reinterpret_cast<bf16x8*>(&Bs[r * 72 + c8]) = cvt8(v0, v1);
            }
            __syncthreads();
#pragma unroll
            for (int kk = 0; kk < 2; ++kk) {
                bf16x8 af[2], bfr[3];
#pragma unroll
                for (int i = 0; i < 2; ++i)
                    af[i] = *reinterpret_cast<const bf16x8*>(
                        &As[(wr * 32 + i * 16 + col) * 72 + kk * 32 + kg * 8]);
#pragma unroll
                for (int j = 0; j < 3; ++j)
                    bfr[j] = *reinterpret_cast<const bf16x8*>(
                        &Bs[(wc * 48 + j * 16 + col) * 72 + kk * 32 + kg * 8]);
#pragma unroll
                for (int i = 0; i < 2; ++i)
#pragma unroll
                    for (int j = 0; j < 3; ++j)
                        acc[i][j] = __builtin_amdgcn_mfma_f32_16x16x32_bf16(
                            af[i], bfr[j], acc[i][j], 0, 0, 0);
            }
            __syncthreads();
        }
#pragma unroll
        for (int i = 0; i < 2; ++i)
#pragma unroll
            for (int j = 0; j < 3; ++j)
#pragma unroll
                for (int r = 0; r < 4; ++r) {
                    int m = m0 + wr * 32 + i * 16 + kg * 4 + r;
                    int n = n0 + wc * 48 + j * 16 + col;
                    kqvb[(size_t)m * NKV + n] = f2bf(acc[i][j][r]);
                }

        // converters (first 8 blocks): w_out / q_pos / v_posT -> bf16
        if (bid < 8) {
            const int base = bid * 12288;
#pragma unroll
            for (int i = 0; i < 24; ++i) {
                int e = base + i * 512 + tid;
                if (e < 65536) {
                    woutb[e] = f2bf(w_out[e]);
                } else if (e < 81920) {
                    int e2 = e - 65536;
                    int h = e2 >> 12, rr = e2 & 4095, w = rr >> 6, d = rr & 63;
                    qposb[e2] = f2bf(q_pos[(w * HH + h) * DD + d]);
                } else {
                    int e3 = e - 81920;
                    int h = e3 >> 12, rr = e3 & 4095, d = rr >> 6, w = rr & 63;
                    vposTb[e3] = f2bf(v_pos[(w * HH + h) * DD + d]);
                }
            }
        }
    }
    grid.sync();

    // ======================= Phase B: attention =======================
    {
        short* QS = lds;               // [128][72]
        short* VT = lds + 9216;        // [64][152]
        short* PP = lds + 18944;       // 4 x [16][104]
        short* PD = lds + 25600;       // 4 x [16][72]
        float* fb = reinterpret_cast<float*>(lds + 30208);
        float* SB = fb;                // [64][68]
        float* PT = fb + 4352;         // [128][9]
        float* DQ = fb + 5504;         // [128]

        const int tile = bid & 31;
        const int h    = (bid >> 5) & 3;
        const int b    = bid >> 7;
        const int t0   = tile * 64;
        const int j0   = t0 - 63;
        const int j0v  = t0 - 64;
        const short* kqv_b = kqvb + (size_t)(b * TT) * NKV;

        {   // zero PP pads
            unsigned int* pz = reinterpret_cast<unsigned int*>(PP);
#pragma unroll
            for (int i = 0; i < 7; ++i) {
                int fi = tid + i * 512;
                if (fi < 3328) pz[fi] = 0u;
            }
        }
        // stage QS + k.q partials
#pragma unroll
        for (int it = 0; it < 2; ++it) {
            int fi = tid + it * 512;
            int r = fi >> 3, c8 = (fi & 7) << 3;
            int j = j0 + r;
            bf16x8 kv = (bf16x8){0,0,0,0,0,0,0,0};
            bf16x8 qv = (bf16x8){0,0,0,0,0,0,0,0};
            if (j >= 0 && j < TT) {
                const short* base = kqv_b + (size_t)j * NKV + h * DD + c8;
                kv = *reinterpret_cast<const bf16x8*>(base);
                qv = *reinterpret_cast<const bf16x8*>(base + 256);
            }
            *reinterpret_cast<bf16x8*>(&QS[r * 72 + c8]) = qv;
            float s = 0.f;
#pragma unroll
            for (int q = 0; q < 8; ++q) s += bf2f(kv[q]) * bf2f(qv[q]);
            PT[r * 9 + (fi & 7)] = s;
        }
        // stage VT (rotated-bank transpose from row-major kqv V)
#pragma unroll
        for (int it = 0; it < 3; ++it) {
            int fi = tid + it * 512;
            if (fi < 1216) {
                int r = fi >> 3, c = fi & 7, c8 = c << 3;
                int j = j0v + r;
                bf16x8 v = (bf16x8){0,0,0,0,0,0,0,0};
                if (r < 144 && j >= 0 && j < TT)
                    v = *reinterpret_cast<const bf16x8*>(
                        kqv_b + (size_t)j * NKV + 512 + h * DD + c8);
#pragma unroll
                for (int q0 = 0; q0 < 8; ++q0) {
                    int qp = (q0 + c) & 7;
                    VT[(c8 + qp) * 152 + r] = v[qp];
                }
            }
        }
        __syncthreads();

        // dq reduce
        if (tid < 128) {
            float s = 0.f;
#pragma unroll
            for (int g = 0; g < 8; ++g) s += PT[tid * 9 + g];
            DQ[tid] = s;
        }
        // qq MFMA: wave wv -> m-tile wv (16 q rows), scatter band to SB
        {
            f32x4 qa[4];
#pragma unroll
            for (int n = 0; n < 4; ++n) qa[n] = (f32x4){0.f, 0.f, 0.f, 0.f};
#pragma unroll
            for (int ks = 0; ks < 2; ++ks) {
                bf16x8 af = *reinterpret_cast<const bf16x8*>(
                    &QS[(wv * 16 + col) * 72 + ks * 32 + kg * 8]);
#pragma unroll
                for (int n = 0; n < 4; ++n) {
                    bf16x8 bfr = *reinterpret_cast<const bf16x8*>(
                        qposb + h * 4096 + (n * 16 + col) * 64 + ks * 32 + kg * 8);
                    qa[n] = __builtin_amdgcn_mfma_f32_16x16x32_bf16(af, bfr, qa[n], 0, 0, 0);
                }
            }
#pragma unroll
            for (int n = 0; n < 4; ++n) {
                int w = n * 16 + col;
#pragma unroll
                for (int r = 0; r < 4; ++r) {
                    int jl = wv * 16 + kg * 4 + r;
                    int il = jl - w;
                    if (il >= 0 && il < 64) SB[il * 68 + w] = qa[n][r];
                }
            }
        }
        __syncthreads();

        // softmax: 8 rows per wave
#pragma unroll
        for (int i2 = 0; i2 < 2; ++i2) {
            int row = wv * 8 + i2 * 4 + kg;
            int t = t0 + row;
            f32x4 sv = *reinterpret_cast<const f32x4*>(&SB[row * 68 + col * 4]);
            float s4[4];
#pragma unroll
            for (int q = 0; q < 4; ++q) {
                int w = col * 4 + q;
                float s = (sv[q] + DQ[row + w]) * 0.125f;
                if (tile == 0 && row + w < 63) s = -INFINITY;
                s4[q] = s;
            }
            float m = fmaxf(fmaxf(s4[0], s4[1]), fmaxf(s4[2], s4[3]));
#pragma unroll
            for (int off = 8; off; off >>= 1) m = fmaxf(m, __shfl_xor(m, off));
            float p[4], sum = 0.f;
#pragma unroll
            for (int q = 0; q < 4; ++q) { p[q] = __expf(s4[q] - m); sum += p[q]; }
#pragma unroll
            for (int off = 8; off; off >>= 1) sum += __shfl_xor(sum, off);
            float inv = 1.f / sum;
            int rg = row >> 4, i16 = row & 15;
            short* pph = PP + rg * 1664;
            short* pdh = PD + rg * 1152;
#pragma unroll
            for (int q = 0; q < 4; ++q) {
                int w = col * 4 + q;
                float wei = p[q] * inv;
                if (t < TQ)
                    wei_out[(((size_t)b * TQ + t) * WW + w) * HH + h] = wei;
                short wb = f2bf(wei);
                pdh[i16 * 72 + w] = wb;
                pph[i16 * 104 + i16 + w + 1] = wb;   // +1: VT origin t0-64
            }
        }
        __syncthreads();

        // PV MFMA
        {
            const int rg = wv & 3;
            const short* pph = PP + rg * 1664;
            const short* pdh = PD + rg * 1152;
#pragma unroll
            for (int dt2 = 0; dt2 < 2; ++dt2) {
                int dt = (wv >> 2) * 2 + dt2;
                f32x4 pa = (f32x4){0.f, 0.f, 0.f, 0.f};
#pragma unroll
                for (int ks = 0; ks < 3; ++ks) {
                    bf16x8 af = *reinterpret_cast<const bf16x8*>(
                        &pph[col * 104 + ks * 32 + kg * 8]);
                    bf16x8 bfr = *reinterpret_cast<const bf16x8*>(
                        &VT[(dt * 16 + col) * 152 + rg * 16 + ks * 32 + kg * 8]);
                    pa = __builtin_amdgcn_mfma_f32_16x16x32_bf16(af, bfr, pa, 0, 0, 0);
                }
#pragma unroll
                for (int ks = 0; ks < 2; ++ks) {
                    bf16x8 af = *reinterpret_cast<const bf16x8*>(
                        &pdh[col * 72 + ks * 32 + kg * 8]);
                    bf16x8 bfr = *reinterpret_cast<const bf16x8*>(
                        vposTb + h * 4096 + (dt * 16 + col) * 64 + ks * 32 + kg * 8);
                    pa = __builtin_amdgcn_mfma_f32_16x16x32_bf16(af, bfr, pa, 0, 0, 0);
                }
#pragma unroll
                for (int r = 0; r < 4; ++r) {
                    int t = t0 + rg * 16 + kg * 4 + r;
                    if (t < TQ)
                        attnSb[((size_t)(b * TT) + t + 1) * CC + h * DD + dt * 16 + col] =
                            f2bf(pa[r]);
                }
            }
        }
    }
    grid.sync();

    // ======================= Phase C: output GEMM =======================
    {
        short* As = lds;            // [16][72]
        short* Bs = lds + 1152;     // [256][72]
        const int m0 = bid * 16;

        f32x4 acc[2];
#pragma unroll
        for (int j = 0; j < 2; ++j) acc[j] = (f32x4){0.f, 0.f, 0.f, 0.f};

        for (int k0 = 0; k0 < 256; k0 += 64) {
            if (tid < 128) {
                int r = tid >> 3, c8 = (tid & 7) << 3;
                int gr = m0 + r;
                bf16x8 sv = (bf16x8){0,0,0,0,0,0,0,0};
                if ((gr & (TT - 1)) != 0)
                    sv = *reinterpret_cast<const bf16x8*>(
                        attnSb + (size_t)gr * 256 + k0 + c8);
                *reinterpret_cast<bf16x8*>(&As[r * 72 + c8]) = sv;
            }
#pragma unroll
            for (int it = 0; it < 4; ++it) {
                int fi = tid + it * 512;
                int r = fi >> 3, c8 = (fi & 7) << 3;
                *reinterpret_cast<bf16x8*>(&Bs[r * 72 + c8]) =
                    *reinterpret_cast<const bf16x8*>(woutb + (size_t)r * 256 + k0 + c8);
            }
            __syncthreads();
#pragma unroll
            for (int kk = 0; kk < 2; ++kk) {
                bf16x8 af = *reinterpret_cast<const bf16x8*>(
                    &As[col * 72 + kk * 32 + kg * 8]);
#pragma unroll
                for (int j = 0; j < 2; ++j) {
                    bf16x8 bfr = *reinterpret_cast<const bf16x8*>(
                        &Bs[(wv * 32 + j * 16 + col) * 72 + kk * 32 + kg * 8]);
                    acc[j] = __builtin_amdgcn_mfma_f32_16x16x32_bf16(af, bfr, acc[j], 0, 0, 0);
                }
            }
            __syncthreads();
        }
#pragma unroll
        for (int j = 0; j < 2; ++j)
#pragma unroll
            for (int r = 0; r < 4; ++r) {
                int m = m0 + kg * 4 + r;
                int n = wv * 32 + j * 16 + col;
                y[(size_t)m * 256 + n] = acc[j][r] + b_out[n];
            }
    }
}

// ---------------------------------------------------------------------------
extern "C" void kernel_launch(void* const* d_in, const int* in_sizes, int n_in,
                              void* d_out, int out_size, void* d_ws, size_t ws_size,
                              hipStream_t stream) {
    const float* x     = (const float*)d_in[0];
    const float* w_kqv = (const float*)d_in[1];
    const float* w_out = (const float*)d_in[2];
    const float* b_out = (const float*)d_in[3];
    const float* q_pos = (const float*)d_in[4];
    const float* v_pos = (const float*)d_in[5];

    float* y   = (float*)d_out;
    float* wei = (float*)d_out + (size_t)BB * TT * CC;

    short* kqvb   = (short*)d_ws;                          // bf16 (B*T, 768)
    short* woutb  = kqvb + (size_t)BB * TT * NKV;          // bf16 (256,256)
    short* qposb  = woutb + 65536;                         // bf16 [h][w][d]
    short* vposTb = qposb + 16384;                         // bf16 [h][d][w]
    short* attnSb = vposTb + 16384;                        // bf16 (B*T, 256)

    void* kargs[] = {
        (void*)&x, (void*)&w_kqv, (void*)&w_out, (void*)&b_out,
        (void*)&q_pos, (void*)&v_pos, (void*)&y, (void*)&wei,
        (void*)&kqvb, (void*)&qposb, (void*)&vposTb, (void*)&woutb,
        (void*)&attnSb
    };
    (void)hipLaunchCooperativeKernel((void*)mega, dim3(256), dim3(512),
                                     kargs, 0, stream);
}

// Round 11
// 42.835 us; speedup vs baseline: 2.7930x; 2.7930x over previous
//
#include <hip/hip_runtime.h>
#include <hip/hip_bf16.h>
#include <math.h>

#define BB 2
#define TT 2048
#define CC 256
#define HH 4
#define DD 64
#define WW 64
#define TQ 2047
#define NKV 768

typedef __attribute__((ext_vector_type(8))) short bf16x8;
typedef __attribute__((ext_vector_type(4))) float f32x4;

__device__ inline short f2bf(float x) {
    unsigned u = __float_as_uint(x);
    u += 0x7FFF + ((u >> 16) & 1);
    return (short)(u >> 16);
}
__device__ inline float bf2f(short s) {
    return __uint_as_float(((unsigned)(unsigned short)s) << 16);
}
__device__ inline bf16x8 cvt8(float4 a, float4 b) {
    bf16x8 r;
    r[0] = f2bf(a.x); r[1] = f2bf(a.y); r[2] = f2bf(a.z); r[3] = f2bf(a.w);
    r[4] = f2bf(b.x); r[5] = f2bf(b.y); r[6] = f2bf(b.z); r[7] = f2bf(b.w);
    return r;
}

// ---------------------------------------------------------------------------
// K1: kqv = x @ w_kqv^T (f32 in, bf16 out), BM=64 BN=96 BK=64, grid (65, 8).
// blockIdx.x == 64 -> 8 converter blocks: w_out/q_pos/v_posT -> bf16.
// ---------------------------------------------------------------------------
__global__ __launch_bounds__(256)
void gemm_kqv(const float* __restrict__ Av, const float* __restrict__ Bv,
              short* __restrict__ Cb,
              const float* __restrict__ qposf, const float* __restrict__ vposf,
              const float* __restrict__ woutf,
              short* __restrict__ qposb, short* __restrict__ vposTb,
              short* __restrict__ woutb) {
    constexpr int BM = 64, BN = 96, LDA = 72;
    __shared__ short As[BM][LDA];
    __shared__ short Bs[BN][LDA];

    const int tid = threadIdx.x;

    if ((int)blockIdx.x == 64) {     // converters
        const int base = blockIdx.y * 12288;
#pragma unroll
        for (int i = 0; i < 48; ++i) {
            int e = base + i * 256 + tid;
            if (e < 65536) {
                woutb[e] = f2bf(woutf[e]);
            } else if (e < 81920) {
                int e2 = e - 65536;
                int h = e2 >> 12, r = e2 & 4095, w = r >> 6, d = r & 63;
                qposb[e2] = f2bf(qposf[(w * HH + h) * DD + d]);
            } else {
                int e3 = e - 81920;
                int h = e3 >> 12, r = e3 & 4095, d = r >> 6, w = r & 63;
                vposTb[e3] = f2bf(vposf[(w * HH + h) * DD + d]);
            }
        }
        return;
    }

    const int m0 = blockIdx.x * BM, n0 = blockIdx.y * BN;
    const int wv = tid >> 6, lane = tid & 63;
    const int wr = wv >> 1, wc = wv & 1;
    const int col = lane & 15, kg = lane >> 4;

    f32x4 acc[2][3];
#pragma unroll
    for (int i = 0; i < 2; ++i)
#pragma unroll
        for (int j = 0; j < 3; ++j) acc[i][j] = (f32x4){0.f, 0.f, 0.f, 0.f};

    for (int k0 = 0; k0 < 256; k0 += 64) {
#pragma unroll
        for (int it = 0; it < 2; ++it) {
            int fi = tid + it * 256;
            int r = fi >> 3, c8 = (fi & 7) << 3;
            const float* ap = Av + (size_t)(m0 + r) * 256 + k0 + c8;
            float4 v0 = *reinterpret_cast<const float4*>(ap);
            float4 v1 = *reinterpret_cast<const float4*>(ap + 4);
            *reinterpret_cast<bf16x8*>(&As[r][c8]) = cvt8(v0, v1);
        }
#pragma unroll
        for (int it = 0; it < 3; ++it) {
            int fi = tid + it * 256;
            int r = fi >> 3, c8 = (fi & 7) << 3;
            const float* bp = Bv + (size_t)(n0 + r) * 256 + k0 + c8;
            float4 v0 = *reinterpret_cast<const float4*>(bp);
            float4 v1 = *reinterpret_cast<const float4*>(bp + 4);
            *reinterpret_cast<bf16x8*>(&Bs[r][c8]) = cvt8(v0, v1);
        }
        __syncthreads();

#pragma unroll
        for (int kk = 0; kk < 2; ++kk) {
            bf16x8 af[2], bfr[3];
#pragma unroll
            for (int i = 0; i < 2; ++i)
                af[i] = *reinterpret_cast<const bf16x8*>(
                    &As[wr * 32 + i * 16 + col][kk * 32 + kg * 8]);
#pragma unroll
            for (int j = 0; j < 3; ++j)
                bfr[j] = *reinterpret_cast<const bf16x8*>(
                    &Bs[wc * 48 + j * 16 + col][kk * 32 + kg * 8]);
#pragma unroll
            for (int i = 0; i < 2; ++i)
#pragma unroll
                for (int j = 0; j < 3; ++j)
                    acc[i][j] = __builtin_amdgcn_mfma_f32_16x16x32_bf16(
                        af[i], bfr[j], acc[i][j], 0, 0, 0);
        }
        __syncthreads();
    }

#pragma unroll
    for (int i = 0; i < 2; ++i)
#pragma unroll
        for (int j = 0; j < 3; ++j)
#pragma unroll
            for (int r = 0; r < 4; ++r) {
                int m = m0 + wr * 32 + i * 16 + kg * 4 + r;
                int n = n0 + wc * 48 + j * 16 + col;
                Cb[(size_t)m * NKV + n] = f2bf(acc[i][j][r]);
            }
}

// ---------------------------------------------------------------------------
// K2: fused attention.  Block = (b, h, 64-row t tile): 256 blocks x 512 thr.
// LDS (shorts, 41472 = 82944 B):
//   QS @0      [128][72]  q rows bf16
//   VT @9216   [64][152]  V^T, col origin j0v = t0-64, cols 0..143 valid
//   PP @18944  4 x [16][104] banded P'
//   PD @25600  4 x [16][72]  dense P
//   @30208 floats: SB[64*68] | PT[128*9] | DQ[128]
// ---------------------------------------------------------------------------
#define LDS_SHORTS 41472

__global__ __launch_bounds__(512)
void attn_fused(const short* __restrict__ kqvb, const short* __restrict__ qposb,
                const short* __restrict__ vposTb, float* __restrict__ wei_out,
                short* __restrict__ attnSb) {
    __shared__ __align__(16) short lds[LDS_SHORTS];
    short* QS = lds;
    short* VT = lds + 9216;
    short* PP = lds + 18944;
    short* PD = lds + 25600;
    float* fb = reinterpret_cast<float*>(lds + 30208);
    float* SB = fb;              // [64][68]
    float* PT = fb + 4352;       // [128][9]
    float* DQ = fb + 5504;       // [128]

    const int tid  = threadIdx.x;
    const int wv   = tid >> 6;
    const int lane = tid & 63;
    const int col  = lane & 15;
    const int kg   = lane >> 4;
    const int bid  = blockIdx.x;
    const int tile = bid & 31;
    const int h    = (bid >> 5) & 3;
    const int b    = bid >> 7;
    const int t0   = tile * 64;
    const int j0   = t0 - 63;
    const int j0v  = t0 - 64;
    const short* kqv_b = kqvb + (size_t)(b * TT) * NKV;

    // ---- zero PP pads
    {
        unsigned int* pz = reinterpret_cast<unsigned int*>(PP);
#pragma unroll
        for (int i = 0; i < 7; ++i) {
            int fi = tid + i * 512;
            if (fi < 3328) pz[fi] = 0u;
        }
    }
    // ---- stage QS (128 q rows) + k.q partials
#pragma unroll
    for (int it = 0; it < 2; ++it) {
        int fi = tid + it * 512;
        int r = fi >> 3, c8 = (fi & 7) << 3;
        int j = j0 + r;
        bf16x8 kv = (bf16x8){0,0,0,0,0,0,0,0};
        bf16x8 qv = (bf16x8){0,0,0,0,0,0,0,0};
        if (j >= 0 && j < TT) {
            const short* base = kqv_b + (size_t)j * NKV + h * DD + c8;
            kv = *reinterpret_cast<const bf16x8*>(base);
            qv = *reinterpret_cast<const bf16x8*>(base + 256);
        }
        *reinterpret_cast<bf16x8*>(&QS[r * 72 + c8]) = qv;
        float s = 0.f;
#pragma unroll
        for (int q = 0; q < 8; ++q) s += bf2f(kv[q]) * bf2f(qv[q]);
        PT[r * 9 + (fi & 7)] = s;
    }
    // ---- stage VT rows 0..143 (rotated-bank transpose)
#pragma unroll
    for (int it = 0; it < 3; ++it) {
        int fi = tid + it * 512;
        if (fi < 1152) {
            int r = fi >> 3, c = fi & 7, c8 = c << 3;
            int j = j0v + r;
            bf16x8 v = (bf16x8){0,0,0,0,0,0,0,0};
            if (j >= 0 && j < TT)
                v = *reinterpret_cast<const bf16x8*>(
                    kqv_b + (size_t)j * NKV + 512 + h * DD + c8);
#pragma unroll
            for (int q0 = 0; q0 < 8; ++q0) {
                int qp = (q0 + c) & 7;
                VT[(c8 + qp) * 152 + r] = v[qp];
            }
        }
    }
    __syncthreads();

    // ---- dq reduce
    if (tid < 128) {
        float s = 0.f;
#pragma unroll
        for (int g = 0; g < 8; ++g) s += PT[tid * 9 + g];
        DQ[tid] = s;
    }
    // ---- qq MFMA: wave wv -> 16 q rows, scatter band to SB
    {
        f32x4 qa[4];
#pragma unroll
        for (int n = 0; n < 4; ++n) qa[n] = (f32x4){0.f, 0.f, 0.f, 0.f};
#pragma unroll
        for (int ks = 0; ks < 2; ++ks) {
            bf16x8 af = *reinterpret_cast<const bf16x8*>(
                &QS[(wv * 16 + col) * 72 + ks * 32 + kg * 8]);
#pragma unroll
            for (int n = 0; n < 4; ++n) {
                bf16x8 bfr = *reinterpret_cast<const bf16x8*>(
                    qposb + h * 4096 + (n * 16 + col) * 64 + ks * 32 + kg * 8);
                qa[n] = __builtin_amdgcn_mfma_f32_16x16x32_bf16(af, bfr, qa[n], 0, 0, 0);
            }
        }
#pragma unroll
        for (int n = 0; n < 4; ++n) {
            int w = n * 16 + col;
#pragma unroll
            for (int r = 0; r < 4; ++r) {
                int jl = wv * 16 + kg * 4 + r;
                int il = jl - w;
                if (il >= 0 && il < 64) SB[il * 68 + w] = qa[n][r];
            }
        }
    }
    __syncthreads();

    // ---- softmax: 8 rows per wave
#pragma unroll
    for (int i2 = 0; i2 < 2; ++i2) {
        int row = wv * 8 + i2 * 4 + kg;
        int t = t0 + row;
        f32x4 sv = *reinterpret_cast<const f32x4*>(&SB[row * 68 + col * 4]);
        float s4[4];
#pragma unroll
        for (int q = 0; q < 4; ++q) {
            int w = col * 4 + q;
            float s = (sv[q] + DQ[row + w]) * 0.125f;
            if (tile == 0 && row + w < 63) s = -INFINITY;
            s4[q] = s;
        }
        float m = fmaxf(fmaxf(s4[0], s4[1]), fmaxf(s4[2], s4[3]));
#pragma unroll
        for (int off = 8; off; off >>= 1) m = fmaxf(m, __shfl_xor(m, off));
        float p[4], sum = 0.f;
#pragma unroll
        for (int q = 0; q < 4; ++q) { p[q] = __expf(s4[q] - m); sum += p[q]; }
#pragma unroll
        for (int off = 8; off; off >>= 1) sum += __shfl_xor(sum, off);
        float inv = 1.f / sum;
        int rg = row >> 4, i16 = row & 15;
        short* pph = PP + rg * 1664;
        short* pdh = PD + rg * 1152;
#pragma unroll
        for (int q = 0; q < 4; ++q) {
            int w = col * 4 + q;
            float wei = p[q] * inv;
            if (t < TQ)
                wei_out[(((size_t)b * TQ + t) * WW + w) * HH + h] = wei;
            short wb = f2bf(wei);
            pdh[i16 * 72 + w] = wb;
            pph[i16 * 104 + i16 + w + 1] = wb;   // +1: VT origin t0-64
        }
    }
    __syncthreads();

    // ---- PV MFMA -> attnS (bf16, shifted by +1 row)
    {
        const int rg = wv & 3;
        const short* pph = PP + rg * 1664;
        const short* pdh = PD + rg * 1152;
#pragma unroll
        for (int dt2 = 0; dt2 < 2; ++dt2) {
            int dt = (wv >> 2) * 2 + dt2;
            f32x4 pa = (f32x4){0.f, 0.f, 0.f, 0.f};
#pragma unroll
            for (int ks = 0; ks < 3; ++ks) {
                bf16x8 af = *reinterpret_cast<const bf16x8*>(
                    &pph[col * 104 + ks * 32 + kg * 8]);
                bf16x8 bfr = *reinterpret_cast<const bf16x8*>(
                    &VT[(dt * 16 + col) * 152 + rg * 16 + ks * 32 + kg * 8]);
                pa = __builtin_amdgcn_mfma_f32_16x16x32_bf16(af, bfr, pa, 0, 0, 0);
            }
#pragma unroll
            for (int ks = 0; ks < 2; ++ks) {
                bf16x8 af = *reinterpret_cast<const bf16x8*>(
                    &pdh[col * 72 + ks * 32 + kg * 8]);
                bf16x8 bfr = *reinterpret_cast<const bf16x8*>(
                    vposTb + h * 4096 + (dt * 16 + col) * 64 + ks * 32 + kg * 8);
                pa = __builtin_amdgcn_mfma_f32_16x16x32_bf16(af, bfr, pa, 0, 0, 0);
            }
#pragma unroll
            for (int r = 0; r < 4; ++r) {
                int t = t0 + rg * 16 + kg * 4 + r;
                if (t < TQ)
                    attnSb[((size_t)(b * TT) + t + 1) * CC + h * DD + dt * 16 + col] =
                        f2bf(pa[r]);
            }
        }
    }
}

// ---------------------------------------------------------------------------
// K3: y = attnS @ w_out^T + b_out.  A bf16 (row m%2048==0 zero), B bf16, f32 out.
// BM=32, BN=64, BK=64 -> grid (128, 4).
// ---------------------------------------------------------------------------
__global__ __launch_bounds__(256)
void gemm_out(const short* __restrict__ Ab, const short* __restrict__ Bb,
              const float* __restrict__ bias, float* __restrict__ C) {
    constexpr int BM = 32, BN = 64, LDA = 72;
    __shared__ short As[BM][LDA];
    __shared__ short Bs[BN][LDA];

    const int tid = threadIdx.x;
    const int m0 = blockIdx.x * BM, n0 = blockIdx.y * BN;
    const int wv = tid >> 6, lane = tid & 63;
    const int wr = wv >> 1, wc = wv & 1;
    const int col = lane & 15, kg = lane >> 4;

    f32x4 acc[2];
#pragma unroll
    for (int j = 0; j < 2; ++j) acc[j] = (f32x4){0.f, 0.f, 0.f, 0.f};

    for (int k0 = 0; k0 < 256; k0 += 64) {
        {
            int r = tid >> 3, c8 = (tid & 7) << 3;
            int gr = m0 + r;
            bf16x8 sv = (bf16x8){0,0,0,0,0,0,0,0};
            if ((gr & (TT - 1)) != 0)
                sv = *reinterpret_cast<const bf16x8*>(Ab + (size_t)gr * 256 + k0 + c8);
            *reinterpret_cast<bf16x8*>(&As[r][c8]) = sv;
        }
#pragma unroll
        for (int it = 0; it < 2; ++it) {
            int fi = tid + it * 256;
            int r = fi >> 3, c8 = (fi & 7) << 3;
            *reinterpret_cast<bf16x8*>(&Bs[r][c8]) =
                *reinterpret_cast<const bf16x8*>(Bb + (size_t)(n0 + r) * 256 + k0 + c8);
        }
        __syncthreads();

#pragma unroll
        for (int kk = 0; kk < 2; ++kk) {
            bf16x8 af = *reinterpret_cast<const bf16x8*>(
                &As[wr * 16 + col][kk * 32 + kg * 8]);
#pragma unroll
            for (int j = 0; j < 2; ++j) {
                bf16x8 bfr = *reinterpret_cast<const bf16x8*>(
                    &Bs[wc * 32 + j * 16 + col][kk * 32 + kg * 8]);
                acc[j] = __builtin_amdgcn_mfma_f32_16x16x32_bf16(af, bfr, acc[j], 0, 0, 0);
            }
        }
        __syncthreads();
    }

#pragma unroll
    for (int j = 0; j < 2; ++j)
#pragma unroll
        for (int r = 0; r < 4; ++r) {
            int m = m0 + wr * 16 + kg * 4 + r;
            int n = n0 + wc * 32 + j * 16 + col;
            C[(size_t)m * 256 + n] = acc[j][r] + bias[n];
        }
}

// ---------------------------------------------------------------------------
extern "C" void kernel_launch(void* const* d_in, const int* in_sizes, int n_in,
                              void* d_out, int out_size, void* d_ws, size_t ws_size,
                              hipStream_t stream) {
    const float* x     = (const float*)d_in[0];
    const float* w_kqv = (const float*)d_in[1];
    const float* w_out = (const float*)d_in[2];
    const float* b_out = (const float*)d_in[3];
    const float* q_pos = (const float*)d_in[4];
    const float* v_pos = (const float*)d_in[5];

    float* y   = (float*)d_out;
    float* wei = (float*)d_out + (size_t)BB * TT * CC;

    short* kqvb   = (short*)d_ws;                          // bf16 (B*T, 768)
    short* woutb  = kqvb + (size_t)BB * TT * NKV;          // bf16 (256,256)
    short* qposb  = woutb + 65536;                         // bf16 [h][w][d]
    short* vposTb = qposb + 16384;                         // bf16 [h][d][w]
    short* attnSb = vposTb + 16384;                        // bf16 (B*T, 256)

    // K1: kqv GEMM + constant converters
    gemm_kqv<<<dim3(65, 8), 256, 0, stream>>>(
        x, w_kqv, kqvb, q_pos, v_pos, w_out, qposb, vposTb, woutb);

    // K2: fused attention -> wei + attnS (bf16)
    attn_fused<<<BB * HH * 32, 512, 0, stream>>>(
        kqvb, qposb, vposTb, wei, attnSb);

    // K3: output projection
    gemm_out<<<dim3((BB * TT) / 32, CC / 64), 256, 0, stream>>>(
        attnSb, woutb, b_out, y);
}

// Round 12
// 34.993 us; speedup vs baseline: 3.4189x; 1.2241x over previous
//
#include <hip/hip_runtime.h>
#include <hip/hip_bf16.h>
#include <math.h>

#define BB 2
#define TT 2048
#define CC 256
#define HH 4
#define DD 64
#define WW 64
#define TQ 2047
#define N_KQV 768

typedef __attribute__((ext_vector_type(8))) short bf16x8;
typedef __attribute__((ext_vector_type(4))) float f32x4;

__device__ inline short f2bf(float x) {
    unsigned u = __float_as_uint(x);
    u += 0x7FFF + ((u >> 16) & 1);
    return (short)(u >> 16);
}
__device__ inline float bf2f(short s) {
    return __uint_as_float(((unsigned)(unsigned short)s) << 16);
}
__device__ inline bf16x8 cvt8(float4 a, float4 b) {
    bf16x8 r;
    r[0] = f2bf(a.x); r[1] = f2bf(a.y); r[2] = f2bf(a.z); r[3] = f2bf(a.w);
    r[4] = f2bf(b.x); r[5] = f2bf(b.y); r[6] = f2bf(b.z); r[7] = f2bf(b.w);
    return r;
}

// ---------------------------------------------------------------------------
// bf16-MFMA GEMM: C[M,N] = A[M,K] @ B[N,K]^T (+bias).  BK=64.
// A: f32 (converted in staging) or bf16 per ABF.  B: f32 weights.
// C: bf16 or f32 per CBF.  ZROW: rows with (m % 2048)==0 read as zero.
// ---------------------------------------------------------------------------
template<bool ABF, int BM, int BN, int WR, int WC, bool ZROW, bool BIAS, bool CBF>
__global__ __launch_bounds__(256)
void gemm_mfma(const void* __restrict__ Av, const float* __restrict__ Bm,
               const float* __restrict__ bias, void* __restrict__ Cv,
               int M, int N, int K) {
    constexpr int BK = 64;
    constexpr int LDA = BK + 8;
    constexpr int MR = BM / (WR * 16);
    constexpr int NR = BN / (WC * 16);
    __shared__ short As[BM][LDA];
    __shared__ short Bs[BN][LDA];

    const int tid = threadIdx.x;
    const int m0 = blockIdx.x * BM, n0 = blockIdx.y * BN;
    const int wv = tid >> 6, lane = tid & 63;
    const int wr = wv / WC, wc = wv % WC;
    const int col = lane & 15, kg = lane >> 4;

    f32x4 acc[MR][NR];
#pragma unroll
    for (int i = 0; i < MR; ++i)
#pragma unroll
        for (int j = 0; j < NR; ++j) acc[i][j] = (f32x4){0.f, 0.f, 0.f, 0.f};

    for (int k0 = 0; k0 < K; k0 += BK) {
#pragma unroll
        for (int it = 0; it < BM / 32; ++it) {
            int fi = tid + it * 256;
            int r = fi >> 3, c8 = (fi & 7) << 3;
            int gr = m0 + r;
            bf16x8 sv;
            if (ZROW && ((gr & (TT - 1)) == 0)) {
                sv = (bf16x8){0, 0, 0, 0, 0, 0, 0, 0};
            } else if constexpr (ABF) {
                sv = *reinterpret_cast<const bf16x8*>(
                    (const short*)Av + (size_t)gr * K + k0 + c8);
            } else {
                const float* ap = (const float*)Av + (size_t)gr * K + k0 + c8;
                float4 v0 = *reinterpret_cast<const float4*>(ap);
                float4 v1 = *reinterpret_cast<const float4*>(ap + 4);
                sv = cvt8(v0, v1);
            }
            *reinterpret_cast<bf16x8*>(&As[r][c8]) = sv;
        }
#pragma unroll
        for (int it = 0; it < BN / 32; ++it) {
            int fi = tid + it * 256;
            int r = fi >> 3, c8 = (fi & 7) << 3;
            const float* bp = Bm + (size_t)(n0 + r) * K + k0 + c8;
            float4 v0 = *reinterpret_cast<const float4*>(bp);
            float4 v1 = *reinterpret_cast<const float4*>(bp + 4);
            *reinterpret_cast<bf16x8*>(&Bs[r][c8]) = cvt8(v0, v1);
        }
        __syncthreads();

#pragma unroll
        for (int kk = 0; kk < 2; ++kk) {
            bf16x8 af[MR], bfr[NR];
#pragma unroll
            for (int i = 0; i < MR; ++i)
                af[i] = *reinterpret_cast<const bf16x8*>(
                    &As[wr * MR * 16 + i * 16 + col][kk * 32 + kg * 8]);
#pragma unroll
            for (int j = 0; j < NR; ++j)
                bfr[j] = *reinterpret_cast<const bf16x8*>(
                    &Bs[wc * NR * 16 + j * 16 + col][kk * 32 + kg * 8]);
#pragma unroll
            for (int i = 0; i < MR; ++i)
#pragma unroll
                for (int j = 0; j < NR; ++j)
                    acc[i][j] = __builtin_amdgcn_mfma_f32_16x16x32_bf16(
                        af[i], bfr[j], acc[i][j], 0, 0, 0);
        }
        __syncthreads();
    }

#pragma unroll
    for (int i = 0; i < MR; ++i) {
#pragma unroll
        for (int j = 0; j < NR; ++j) {
#pragma unroll
            for (int r = 0; r < 4; ++r) {
                int m = m0 + wr * MR * 16 + i * 16 + kg * 4 + r;
                int n = n0 + wc * NR * 16 + j * 16 + col;
                float v = acc[i][j][r];
                if (BIAS) v += bias[n];
                if constexpr (CBF)
                    ((short*)Cv)[(size_t)m * N + n] = f2bf(v);
                else
                    ((float*)Cv)[(size_t)m * N + n] = v;
            }
        }
    }
}

// ---------------------------------------------------------------------------
// Fused attention: scores (qq MFMA + dq) -> banded LDS -> softmax -> PV MFMA.
// One block per (b, h, 64-t tile), 4 waves.  j0 = t0-63 (halo of 128 q rows).
// LDS layout (shorts), regions aliased across phases:
//   [0..11264)    phase1-2: QS [128][72];  phase3+: PP 4x[16][104] + PD 4x[16][72]
//   [11264..15872) PS  [64][72]   q_pos bf16
//   [15872..26624) VT  [64][168]  v transposed bf16 (160 j-rows)
//   [26624..31232) VP  [64][72]   v_pos transposed bf16
//   [31232..39936) phase1-2: PT f32 [128][9]; phase3+: SB f32 [64][68]
//   [39936..40192) DQ f32 [128]
// ---------------------------------------------------------------------------
__global__ __launch_bounds__(256)
void attn_fused(const short* __restrict__ kqvb, const float* __restrict__ q_pos,
                const float* __restrict__ v_pos, float* __restrict__ wei_out,
                short* __restrict__ attnSb) {
    __shared__ __align__(16) short lds[40192];
    float* ldsf = reinterpret_cast<float*>(lds);
    short* QS = lds;                 // [128][72]
    short* PP = lds;                 // 4 x [16][104]
    short* PD = lds + 6656;          // 4 x [16][72]
    short* PS = lds + 11264;         // [64][72]
    short* VT = lds + 15872;         // [64][168]
    short* VP = lds + 26624;         // [64][72]
    float* PT = ldsf + 15616;        // [128][9]
    float* SB = ldsf + 15616;        // [64][68]
    float* DQ = ldsf + 19968;        // [128]

    const int tid  = threadIdx.x;
    const int wv   = tid >> 6;
    const int lane = tid & 63;
    const int col  = lane & 15;
    const int kg   = lane >> 4;
    const int bid  = blockIdx.x;
    const int tile = bid & 31;
    const int h    = (bid >> 5) & 3;
    const int b    = bid >> 7;
    const int t0   = tile * 64;
    const int j0   = t0 - 63;

    // ================= phase 1: stage =================
#pragma unroll
    for (int it = 0; it < 4; ++it) {          // QS rows 0..127 + k.q partials
        int fi = tid + it * 256;
        int r = fi >> 3, c8 = (fi & 7) << 3;
        int j = j0 + r;
        bf16x8 qv = (bf16x8){0,0,0,0,0,0,0,0};
        bf16x8 kv = (bf16x8){0,0,0,0,0,0,0,0};
        if (j >= 0 && j < TT) {
            const short* base = kqvb + ((size_t)(b * TT + j)) * N_KQV + h * DD + c8;
            kv = *reinterpret_cast<const bf16x8*>(base);
            qv = *reinterpret_cast<const bf16x8*>(base + 256);
        }
        *reinterpret_cast<bf16x8*>(&QS[r * 72 + c8]) = qv;
        float s = 0.f;
#pragma unroll
        for (int q = 0; q < 8; ++q) s += bf2f(kv[q]) * bf2f(qv[q]);
        PT[r * 9 + (fi & 7)] = s;
    }
#pragma unroll
    for (int it = 0; it < 2; ++it) {          // PS (q_pos)
        int fi = tid + it * 256;
        int r = fi >> 3, c8 = (fi & 7) << 3;
        const float* pp = q_pos + (size_t)(r * HH + h) * DD + c8;
        float4 v0 = *reinterpret_cast<const float4*>(pp);
        float4 v1 = *reinterpret_cast<const float4*>(pp + 4);
        *reinterpret_cast<bf16x8*>(&PS[r * 72 + c8]) = cvt8(v0, v1);
    }
#pragma unroll
    for (int it = 0; it < 5; ++it) {          // VT rows 0..159 (transposed)
        int fi = tid + it * 256;
        int r = fi >> 3, c8 = (fi & 7) << 3;
        int j = j0 + r;
        bf16x8 v = (bf16x8){0,0,0,0,0,0,0,0};
        if (j >= 0 && j < TT)
            v = *reinterpret_cast<const bf16x8*>(
                kqvb + ((size_t)(b * TT + j)) * N_KQV + 512 + h * DD + c8);
#pragma unroll
        for (int q = 0; q < 8; ++q) VT[(c8 + q) * 168 + r] = v[q];
    }
#pragma unroll
    for (int it = 0; it < 2; ++it) {          // VP (v_pos transposed)
        int fi = tid + it * 256;
        int r = fi >> 3, c8 = (fi & 7) << 3;
        const float* pp = v_pos + (size_t)(r * HH + h) * DD + c8;
        float4 v0 = *reinterpret_cast<const float4*>(pp);
        float4 v1 = *reinterpret_cast<const float4*>(pp + 4);
        bf16x8 v = cvt8(v0, v1);
#pragma unroll
        for (int q = 0; q < 8; ++q) VP[(c8 + q) * 72 + r] = v[q];
    }
    __syncthreads();

    // ================= phase 2: qq MFMA + dq reduce =================
    f32x4 qacc[2][4];
#pragma unroll
    for (int mi = 0; mi < 2; ++mi)
#pragma unroll
        for (int n = 0; n < 4; ++n) qacc[mi][n] = (f32x4){0.f, 0.f, 0.f, 0.f};

#pragma unroll
    for (int ks = 0; ks < 2; ++ks) {
        bf16x8 af[2], bfr[4];
#pragma unroll
        for (int mi = 0; mi < 2; ++mi)
            af[mi] = *reinterpret_cast<const bf16x8*>(
                &QS[(wv * 32 + mi * 16 + col) * 72 + ks * 32 + kg * 8]);
#pragma unroll
        for (int n = 0; n < 4; ++n)
            bfr[n] = *reinterpret_cast<const bf16x8*>(
                &PS[(n * 16 + col) * 72 + ks * 32 + kg * 8]);
#pragma unroll
        for (int mi = 0; mi < 2; ++mi)
#pragma unroll
            for (int n = 0; n < 4; ++n)
                qacc[mi][n] = __builtin_amdgcn_mfma_f32_16x16x32_bf16(
                    af[mi], bfr[n], qacc[mi][n], 0, 0, 0);
    }
    if (tid < 128) {
        float s = 0.f;
#pragma unroll
        for (int g = 0; g < 8; ++g) s += PT[tid * 9 + g];
        DQ[tid] = s;
    }
    __syncthreads();   // QS/PT dead after this point

    // ================= phase 3: zero PP/PD, scatter SB =================
    {
        unsigned int* pz = reinterpret_cast<unsigned int*>(lds);
#pragma unroll
        for (int i = 0; i < 22; ++i) pz[tid + i * 256] = 0u;   // 5632 u32
    }
#pragma unroll
    for (int mi = 0; mi < 2; ++mi) {
#pragma unroll
        for (int n = 0; n < 4; ++n) {
            int w = n * 16 + col;
#pragma unroll
            for (int r = 0; r < 4; ++r) {
                int jl = wv * 32 + mi * 16 + kg * 4 + r;
                int it_ = jl - w;
                if (it_ >= 0 && it_ < 64) SB[it_ * 68 + w] = qacc[mi][n][r];
            }
        }
    }
    __syncthreads();

    // ================= phase 4: softmax (4 rows in parallel) =================
    const int rs = lane >> 4;      // row-in-group
    const int wg = lane & 15;      // w quad
    const bool edge = (t0 == 0);
#pragma unroll
    for (int i4 = 0; i4 < 4; ++i4) {
        int i = wv * 16 + i4 * 4 + rs;          // row in [0,64)
        int t = t0 + i;
        f32x4 sv = *reinterpret_cast<const f32x4*>(&SB[i * 68 + wg * 4]);
        float s[4];
#pragma unroll
        for (int q = 0; q < 4; ++q) {
            int w = wg * 4 + q;
            s[q] = (sv[q] + DQ[i + w]) * 0.125f;
            if (edge && (i - 63 + w) < 0) s[q] = -INFINITY;
        }
        float m = fmaxf(fmaxf(s[0], s[1]), fmaxf(s[2], s[3]));
#pragma unroll
        for (int off = 8; off; off >>= 1) m = fmaxf(m, __shfl_xor(m, off));
        float p[4], sum = 0.f;
#pragma unroll
        for (int q = 0; q < 4; ++q) { p[q] = __expf(s[q] - m); sum += p[q]; }
#pragma unroll
        for (int off = 8; off; off >>= 1) sum += __shfl_xor(sum, off);
        float inv = 1.f / sum;
        int il = i4 * 4 + rs;                   // row within wave's 16
#pragma unroll
        for (int q = 0; q < 4; ++q) {
            int w = wg * 4 + q;
            float wei = p[q] * inv;
            if (t < TQ)
                wei_out[(((size_t)b * TQ + t) * WW + w) * HH + h] = wei;
            short wb = f2bf(wei);
            PD[wv * 1152 + il * 72 + w] = wb;
            PP[wv * 1664 + il * 104 + il + w] = wb;
        }
    }
    __syncthreads();

    // ================= phase 5: PV MFMA =================
    f32x4 pacc[4];
#pragma unroll
    for (int dt = 0; dt < 4; ++dt) pacc[dt] = (f32x4){0.f, 0.f, 0.f, 0.f};
    const int jbase = wv * 16;
#pragma unroll
    for (int ks = 0; ks < 3; ++ks) {
        bf16x8 afrag = *reinterpret_cast<const bf16x8*>(
            &PP[wv * 1664 + col * 104 + ks * 32 + kg * 8]);
#pragma unroll
        for (int dt = 0; dt < 4; ++dt) {
            bf16x8 bfrag = *reinterpret_cast<const bf16x8*>(
                &VT[(dt * 16 + col) * 168 + jbase + ks * 32 + kg * 8]);
            pacc[dt] = __builtin_amdgcn_mfma_f32_16x16x32_bf16(afrag, bfrag, pacc[dt], 0, 0, 0);
        }
    }
#pragma unroll
    for (int ks = 0; ks < 2; ++ks) {
        bf16x8 afrag = *reinterpret_cast<const bf16x8*>(
            &PD[wv * 1152 + col * 72 + ks * 32 + kg * 8]);
#pragma unroll
        for (int dt = 0; dt < 4; ++dt) {
            bf16x8 bfrag = *reinterpret_cast<const bf16x8*>(
                &VP[(dt * 16 + col) * 72 + ks * 32 + kg * 8]);
            pacc[dt] = __builtin_amdgcn_mfma_f32_16x16x32_bf16(afrag, bfrag, pacc[dt], 0, 0, 0);
        }
    }

    const int ta = t0 + wv * 16;
#pragma unroll
    for (int dt = 0; dt < 4; ++dt) {
#pragma unroll
        for (int r = 0; r < 4; ++r) {
            int t = ta + kg * 4 + r;
            if (t < TQ)
                attnSb[((size_t)(b * TT) + t + 1) * CC + h * DD + dt * 16 + col] =
                    f2bf(pacc[dt][r]);
        }
    }
}

// ---------------------------------------------------------------------------
extern "C" void kernel_launch(void* const* d_in, const int* in_sizes, int n_in,
                              void* d_out, int out_size, void* d_ws, size_t ws_size,
                              hipStream_t stream) {
    const float* x     = (const float*)d_in[0];
    const float* w_kqv = (const float*)d_in[1];
    const float* w_out = (const float*)d_in[2];
    const float* b_out = (const float*)d_in[3];
    const float* q_pos = (const float*)d_in[4];
    const float* v_pos = (const float*)d_in[5];

    float* y   = (float*)d_out;
    float* wei = (float*)d_out + (size_t)BB * TT * CC;

    short* kqvb   = (short*)d_ws;                          // bf16 (B*T, 768)
    short* attnSb = kqvb + (size_t)BB * TT * N_KQV;        // bf16 (B*T, 256)

    // K1: kqv = x @ w_kqv^T  (bf16 MFMA, bf16 out), 64x96 tiles -> 512 blocks
    gemm_mfma<false, 64, 96, 2, 2, false, false, true>
        <<<dim3((BB * TT) / 64, N_KQV / 96), 256, 0, stream>>>(
            x, w_kqv, nullptr, kqvb, BB * TT, N_KQV, CC);

    // K2: fused scores + softmax + PV
    attn_fused<<<BB * HH * 32, 256, 0, stream>>>(kqvb, q_pos, v_pos, wei, attnSb);

    // K3: y = attnS @ w_out^T + b_out  (32x64 tiles -> 512 blocks)
    gemm_mfma<true, 32, 64, 2, 2, true, true, false>
        <<<dim3((BB * TT) / 32, CC / 64), 256, 0, stream>>>(
            attnSb, w_out, b_out, y, BB * TT, CC, CC);
}